// Round 9
// baseline (110.129 us; speedup 1.0000x reference)
//
#include <hip/hip_runtime.h>

#define CROP_H 14
#define CROP_W 14
#define IMG_B 8
#define IMG_C 256
#define IMG_H 100
#define IMG_W 152
#define NBOX 1000
#define PLANE (IMG_H * IMG_W)                 // 15200
#define POS (CROP_H * CROP_W)                 // 196
#define OUT_PER_BOX (IMG_C * POS)             // 50176
#define BOXCAP 64                             // boxes per param chunk
#define CG 32                                 // fallback path
#define NCG (IMG_C / CG)

typedef float f2u __attribute__((ext_vector_type(2), aligned(4)));

// ---------------------------------------------------------------------------
// Kernel A: stable counting-sort of boxes by box_ind -> perm + per-image
// offsets. Deterministic (atomicOr order-independent, popcount ranks).
// ---------------------------------------------------------------------------
__global__ __launch_bounds__(1024) void sort_boxes_kernel(
    const int* __restrict__ box_ind,
    int* __restrict__ perm,
    int* __restrict__ offsets)            // [IMG_B + 1]
{
    __shared__ unsigned s_mask[IMG_B][32];
    __shared__ int s_tot[IMG_B];
    const int tid = threadIdx.x;

    if (tid < IMG_B * 32) ((unsigned*)s_mask)[tid] = 0u;
    __syncthreads();

    int key = 0;
    if (tid < NBOX) {
        key = box_ind[tid];
        atomicOr(&s_mask[key][tid >> 5], 1u << (tid & 31));
    }
    __syncthreads();

    if (tid < IMG_B) {
        int t = 0;
        #pragma unroll
        for (int w = 0; w < 32; ++w) t += __popc(s_mask[tid][w]);
        s_tot[tid] = t;
    }
    __syncthreads();

    if (tid == 0) {
        int acc = 0;
        #pragma unroll
        for (int k = 0; k < IMG_B; ++k) { offsets[k] = acc; acc += s_tot[k]; }
        offsets[IMG_B] = acc;
    }

    if (tid < NBOX) {
        int base = 0;
        #pragma unroll
        for (int k = 0; k < IMG_B; ++k) base += (k < key) ? s_tot[k] : 0;
        const int w = tid >> 5, b = tid & 31;
        int r = __popc(s_mask[key][w] & ((b == 0) ? 0u : ((1u << b) - 1u)));
        for (int ww = 0; ww < w; ++ww) r += __popc(s_mask[key][ww]);
        perm[base + r] = tid;
    }
}

// ---------------------------------------------------------------------------
// Kernel B: plane-in-LDS crop-and-resize with precomputed row/col packs.
// Block = (channel, image). Plane (60.8 KB) staged once, coalesced; per-box
// row/col interpolation state precomputed per 64-box chunk into LDS float2
// packs. Inner loop: 2 pack b64 reads + 4 plane reads + lerp + coalesced
// store. 1024 threads, 75.6 KB LDS -> 2 blocks/CU = 32 waves/CU.
// ---------------------------------------------------------------------------
__global__ __launch_bounds__(1024, 8) void CropAndResize_16630113370849_kernel(
    const float* __restrict__ image,
    const float* __restrict__ boxes,
    const int* __restrict__ perm,
    const int* __restrict__ offsets,
    float* __restrict__ out)
{
    __shared__ __align__(16) float s_plane[PLANE];
    __shared__ f2u s_row[BOXCAP * CROP_H];     // {bits(off_r|sely<<14|vy<<15), yw}
    __shared__ f2u s_col[BOXCAP * CROP_W];     // {bits(c0|selx<<8|vx<<9), xw}
    __shared__ unsigned s_ob[BOXCAP];          // n * OUT_PER_BOX

    const int c   = blockIdx.x;                // channel 0..255
    const int b   = blockIdx.y;                // image 0..7
    const int tid = threadIdx.x;

    // stage plane: 15200 floats = 3800 float4, coalesced
    {
        const float4* __restrict__ src =
            (const float4*)(image + ((size_t)b * IMG_C + c) * PLANE);
        float4* dst = (float4*)s_plane;
        #pragma unroll
        for (int i = 0; i < 4; ++i) {
            const int e = i * 1024 + tid;
            if (e < PLANE / 4) dst[e] = src[e];
        }
    }

    const int s0 = offsets[b], s1 = offsets[b + 1];
    const unsigned cPOS = (unsigned)(c * POS);

    for (int ck = s0; ck < s1; ck += BOXCAP) {
        const int cnt = min(BOXCAP, s1 - ck);

        __syncthreads();   // plane ready (1st iter) / prev chunk readers done

        // setup: cnt*28 tasks (14 rows + 14 cols per box)
        for (int j = tid; j < cnt * 28; j += 1024) {
            const int slot = j / 28;           // magic mul
            const int t    = j - slot * 28;
            const int n    = perm[ck + slot];
            if (t == 0) s_ob[slot] = (unsigned)(n * OUT_PER_BOX);

            const float y1 = boxes[n * 4 + 0];
            const float x1 = boxes[n * 4 + 1];
            const float y2 = boxes[n * 4 + 2];
            const float x2 = boxes[n * 4 + 3];

            if (t < CROP_H) {
                // exact fp32 RN, no FMA — must match numpy bitwise (validity
                // is a discontinuous function of in_y)
                const float hs   = __fdiv_rn(__fmul_rn(__fsub_rn(y2, y1), (float)(IMG_H - 1)),
                                             (float)(CROP_H - 1));
                const float in_y = __fadd_rn(__fmul_rn(y1, (float)(IMG_H - 1)),
                                             __fmul_rn((float)t, hs));
                const int vy = (in_y >= 0.0f) && (in_y <= (float)(IMG_H - 1));
                const float top = floorf(in_y);
                const float yw  = __fsub_rn(in_y, top);
                const int ti = (int)fminf(fmaxf(top, 0.0f), (float)(IMG_H - 1));
                const int r0 = min(ti, IMG_H - 2);
                const int sely = (ti == IMG_H - 1);
                f2u e; e.x = __int_as_float((r0 * IMG_W) | (sely << 14) | (vy << 15));
                e.y = yw;
                s_row[slot * CROP_H + t] = e;
            } else {
                const int x = t - CROP_H;
                const float ws   = __fdiv_rn(__fmul_rn(__fsub_rn(x2, x1), (float)(IMG_W - 1)),
                                             (float)(CROP_W - 1));
                const float in_x = __fadd_rn(__fmul_rn(x1, (float)(IMG_W - 1)),
                                             __fmul_rn((float)x, ws));
                const int vx = (in_x >= 0.0f) && (in_x <= (float)(IMG_W - 1));
                const float left = floorf(in_x);
                const float xw   = __fsub_rn(in_x, left);
                const int li = (int)fminf(fmaxf(left, 0.0f), (float)(IMG_W - 1));
                const int c0 = min(li, IMG_W - 2);
                const int selx = (li == IMG_W - 1);
                f2u e; e.x = __int_as_float(c0 | (selx << 8) | (vx << 9));
                e.y = xw;
                s_col[slot * CROP_W + x] = e;
            }
        }
        __syncthreads();

        const int total = cnt * POS;
        #pragma unroll 2
        for (int idx = tid; idx < total; idx += 1024) {
            const int slot = idx / POS;          // magic mul
            const int p    = idx - slot * POS;
            const int y    = p / CROP_W;         // magic mul
            const int x    = p - y * CROP_W;

            const f2u re = s_row[slot * CROP_H + y];
            const f2u ce = s_col[slot * CROP_W + x];
            const int ri = __float_as_int(re.x);
            const int ci = __float_as_int(ce.x);

            const int off = (ri & 0x3FFF) + (ci & 0xFF);
            const float a0 = s_plane[off];
            const float a1 = s_plane[off + 1];
            const float b0 = s_plane[off + IMG_W];
            const float b1 = s_plane[off + IMG_W + 1];

            const float tA = (ri & 0x4000) ? b0 : a0;   // sely
            const float tB = (ri & 0x4000) ? b1 : a1;
            const float tl = (ci & 0x100)  ? tB : tA;   // selx
            const float bl = (ci & 0x100)  ? b1 : b0;

            const float top_v = __fadd_rn(tl, __fmul_rn(__fsub_rn(tB, tl), ce.y));
            const float bot_v = __fadd_rn(bl, __fmul_rn(__fsub_rn(b1, bl), ce.y));
            const float v = __fadd_rn(top_v, __fmul_rn(__fsub_rn(bot_v, top_v), re.y));

            const bool vald = (ri & 0x8000) && (ci & 0x200);
            out[(size_t)(s_ob[slot] + cPOS + (unsigned)p)] = vald ? v : 0.0f;
        }
    }
}

// ---------------------------------------------------------------------------
// Fallback (R5 structure, known 104 us) if workspace is too small.
// ---------------------------------------------------------------------------
__global__ __launch_bounds__(256) void crop_chw_kernel(
    const float* __restrict__ image,
    const float* __restrict__ boxes,
    const int* __restrict__ box_ind,
    float* __restrict__ out)
{
    const int bid  = blockIdx.x;
    const int cg   = bid & 7;
    const int n    = bid >> 3;
    const int tid  = threadIdx.x;
    if (tid >= POS) return;

    const int b = box_ind[n];
    const int y = tid / CROP_W;
    const int x = tid - y * CROP_W;

    const float y1 = boxes[n * 4 + 0];
    const float x1 = boxes[n * 4 + 1];
    const float y2 = boxes[n * 4 + 2];
    const float x2 = boxes[n * 4 + 3];

    const float hs   = __fdiv_rn(__fmul_rn(__fsub_rn(y2, y1), (float)(IMG_H - 1)),
                                 (float)(CROP_H - 1));
    const float in_y = __fadd_rn(__fmul_rn(y1, (float)(IMG_H - 1)),
                                 __fmul_rn((float)y, hs));
    const int vy = (in_y >= 0.0f) && (in_y <= (float)(IMG_H - 1));
    const float top = floorf(in_y);
    const float yw  = __fsub_rn(in_y, top);
    const int ti = (int)fminf(fmaxf(top, 0.0f), (float)(IMG_H - 1));

    const float ws   = __fdiv_rn(__fmul_rn(__fsub_rn(x2, x1), (float)(IMG_W - 1)),
                                 (float)(CROP_W - 1));
    const float in_x = __fadd_rn(__fmul_rn(x1, (float)(IMG_W - 1)),
                                 __fmul_rn((float)x, ws));
    const int vx = (in_x >= 0.0f) && (in_x <= (float)(IMG_W - 1));
    const float left = floorf(in_x);
    const float xw   = __fsub_rn(in_x, left);
    const int li = (int)fminf(fmaxf(left, 0.0f), (float)(IMG_W - 1));

    const int r0 = min(ti, IMG_H - 2);
    const int c0 = min(li, IMG_W - 2);
    const bool sely = (ti == IMG_H - 1);
    const bool selx = (li == IMG_W - 1);
    const bool vald = (vy & vx) != 0;

    const float* __restrict__ pl =
        image + (size_t)b * (size_t)(IMG_C * PLANE)
              + (size_t)(cg * CG) * PLANE + (r0 * IMG_W + c0);
    float* __restrict__ po =
        out + (size_t)n * (size_t)OUT_PER_BOX + (size_t)(cg * CG) * POS + tid;

    #pragma unroll 8
    for (int cl = 0; cl < CG; ++cl) {
        const f2u ra = *(const f2u*)(pl);
        const f2u rb = *(const f2u*)(pl + IMG_W);
        const float tA = sely ? rb.x : ra.x;
        const float tB = sely ? rb.y : ra.y;
        const float tl = selx ? tB : tA;
        const float bl = selx ? rb.y : rb.x;
        const float top_v = __fadd_rn(tl, __fmul_rn(__fsub_rn(tB, tl), xw));
        const float bot_v = __fadd_rn(bl, __fmul_rn(__fsub_rn(rb.y, bl), xw));
        const float v = __fadd_rn(top_v, __fmul_rn(__fsub_rn(bot_v, top_v), yw));
        *po = vald ? v : 0.0f;
        pl += PLANE;
        po += POS;
    }
}

extern "C" void kernel_launch(void* const* d_in, const int* in_sizes, int n_in,
                              void* d_out, int out_size, void* d_ws, size_t ws_size,
                              hipStream_t stream) {
    const float* image  = (const float*)d_in[0];
    const float* boxes  = (const float*)d_in[1];
    const int*   boxind = (const int*)d_in[2];
    float* out = (float*)d_out;

    const size_t need = (NBOX + IMG_B + 1) * sizeof(int);
    if (ws_size >= need) {
        int* perm    = (int*)d_ws;
        int* offsets = perm + NBOX;

        sort_boxes_kernel<<<1, 1024, 0, stream>>>(boxind, perm, offsets);
        CropAndResize_16630113370849_kernel<<<dim3(IMG_C, IMG_B), 1024, 0, stream>>>(
            image, boxes, perm, offsets, out);
    } else {
        crop_chw_kernel<<<dim3(NBOX * NCG), 256, 0, stream>>>(
            image, boxes, boxind, out);
    }
}

// Round 10
// 100.081 us; speedup vs baseline: 1.1004x; 1.1004x over previous
//
#include <hip/hip_runtime.h>

#define CROP_H 14
#define CROP_W 14
#define IMG_B 8
#define IMG_C 256
#define IMG_H 100
#define IMG_W 152
#define NBOX 1000
#define PLANE (IMG_H * IMG_W)                 // 15200
#define POS (CROP_H * CROP_W)                 // 196
#define PAIRS (POS / 2)                       // 98 float2 outputs per (box,ch)
#define OUT_PER_BOX (IMG_C * POS)             // 50176
#define BOXCAP 64                             // boxes per param chunk
#define CG 32                                 // fallback path
#define NCG (IMG_C / CG)

typedef float f2u __attribute__((ext_vector_type(2), aligned(8)));
typedef float f4u __attribute__((ext_vector_type(4), aligned(16)));

// ---------------------------------------------------------------------------
// Kernel A: stable counting-sort of boxes by box_ind -> perm + per-image
// offsets. Deterministic (atomicOr order-independent, popcount ranks).
// ---------------------------------------------------------------------------
__global__ __launch_bounds__(1024) void sort_boxes_kernel(
    const int* __restrict__ box_ind,
    int* __restrict__ perm,
    int* __restrict__ offsets)            // [IMG_B + 1]
{
    __shared__ unsigned s_mask[IMG_B][32];
    __shared__ int s_tot[IMG_B];
    const int tid = threadIdx.x;

    if (tid < IMG_B * 32) ((unsigned*)s_mask)[tid] = 0u;
    __syncthreads();

    int key = 0;
    if (tid < NBOX) {
        key = box_ind[tid];
        atomicOr(&s_mask[key][tid >> 5], 1u << (tid & 31));
    }
    __syncthreads();

    if (tid < IMG_B) {
        int t = 0;
        #pragma unroll
        for (int w = 0; w < 32; ++w) t += __popc(s_mask[tid][w]);
        s_tot[tid] = t;
    }
    __syncthreads();

    if (tid == 0) {
        int acc = 0;
        #pragma unroll
        for (int k = 0; k < IMG_B; ++k) { offsets[k] = acc; acc += s_tot[k]; }
        offsets[IMG_B] = acc;
    }

    if (tid < NBOX) {
        int base = 0;
        #pragma unroll
        for (int k = 0; k < IMG_B; ++k) base += (k < key) ? s_tot[k] : 0;
        const int w = tid >> 5, b = tid & 31;
        int r = __popc(s_mask[key][w] & ((b == 0) ? 0u : ((1u << b) - 1u)));
        for (int ww = 0; ww < w; ++ww) r += __popc(s_mask[key][ww]);
        perm[base + r] = tid;
    }
}

// ---------------------------------------------------------------------------
// Kernel B: plane-in-LDS crop-and-resize, 2 outputs per thread.
// Block = (channel, image). Plane (60.8 KB) staged once coalesced. Per-box
// row state (float2: bits,yw) and column-PAIR state (float4:
// bits0,xw0,bits1,xw1) precomputed per 64-box chunk. Inner loop per thread:
// 1 b64 + 1 b128 pack read + 4x ds_read2-fusable plane reads + lerp pair +
// one float2 store (p even -> 8B aligned).
// ---------------------------------------------------------------------------
__global__ __launch_bounds__(1024, 8) void CropAndResize_16630113370849_kernel(
    const float* __restrict__ image,
    const float* __restrict__ boxes,
    const int* __restrict__ perm,
    const int* __restrict__ offsets,
    float* __restrict__ out)
{
    __shared__ __align__(16) float s_plane[PLANE];
    __shared__ f2u s_row[BOXCAP * CROP_H];     // {bits(r0*152|sely<<14|vy<<15), yw}
    __shared__ f4u s_colp[BOXCAP * 7];         // {bits(c0|selx<<8|vx<<9) x2, xw x2}
    __shared__ unsigned s_ob[BOXCAP];          // n * OUT_PER_BOX

    const int c   = blockIdx.x;                // channel 0..255
    const int b   = blockIdx.y;                // image 0..7
    const int tid = threadIdx.x;

    // stage plane: 15200 floats = 3800 float4, coalesced
    {
        const float4* __restrict__ src =
            (const float4*)(image + ((size_t)b * IMG_C + c) * PLANE);
        float4* dst = (float4*)s_plane;
        #pragma unroll
        for (int i = 0; i < 4; ++i) {
            const int e = i * 1024 + tid;
            if (e < PLANE / 4) dst[e] = src[e];
        }
    }

    const int s0 = offsets[b], s1 = offsets[b + 1];
    const unsigned cPOS = (unsigned)(c * POS);

    for (int ck = s0; ck < s1; ck += BOXCAP) {
        const int cnt = min(BOXCAP, s1 - ck);

        __syncthreads();   // plane ready (1st iter) / prev chunk readers done

        // setup: cnt*21 tasks (14 rows + 7 col-pairs per box)
        for (int j = tid; j < cnt * 21; j += 1024) {
            const int slot = j / 21;           // magic mul
            const int t    = j - slot * 21;
            const int n    = perm[ck + slot];
            if (t == 0) s_ob[slot] = (unsigned)(n * OUT_PER_BOX);

            const float y1 = boxes[n * 4 + 0];
            const float x1 = boxes[n * 4 + 1];
            const float y2 = boxes[n * 4 + 2];
            const float x2 = boxes[n * 4 + 3];

            if (t < CROP_H) {
                // exact fp32 RN, no FMA — must match numpy bitwise (validity
                // is a discontinuous function of in_y)
                const float hs   = __fdiv_rn(__fmul_rn(__fsub_rn(y2, y1), (float)(IMG_H - 1)),
                                             (float)(CROP_H - 1));
                const float in_y = __fadd_rn(__fmul_rn(y1, (float)(IMG_H - 1)),
                                             __fmul_rn((float)t, hs));
                const int vy = (in_y >= 0.0f) && (in_y <= (float)(IMG_H - 1));
                const float top = floorf(in_y);
                const float yw  = __fsub_rn(in_y, top);
                const int ti = (int)fminf(fmaxf(top, 0.0f), (float)(IMG_H - 1));
                const int r0 = min(ti, IMG_H - 2);
                const int sely = (ti == IMG_H - 1);
                f2u e; e.x = __int_as_float((r0 * IMG_W) | (sely << 14) | (vy << 15));
                e.y = yw;
                s_row[slot * CROP_H + t] = e;
            } else {
                const int xg = t - CROP_H;     // 0..6
                const float ws = __fdiv_rn(__fmul_rn(__fsub_rn(x2, x1), (float)(IMG_W - 1)),
                                           (float)(CROP_W - 1));
                const float x1W = __fmul_rn(x1, (float)(IMG_W - 1));
                f4u e;
                #pragma unroll
                for (int k = 0; k < 2; ++k) {
                    const int x = 2 * xg + k;
                    const float in_x = __fadd_rn(x1W, __fmul_rn((float)x, ws));
                    const int vx = (in_x >= 0.0f) && (in_x <= (float)(IMG_W - 1));
                    const float left = floorf(in_x);
                    const float xw   = __fsub_rn(in_x, left);
                    const int li = (int)fminf(fmaxf(left, 0.0f), (float)(IMG_W - 1));
                    const int c0 = min(li, IMG_W - 2);
                    const int selx = (li == IMG_W - 1);
                    const int bits = c0 | (selx << 8) | (vx << 9);
                    if (k == 0) { e.x = __int_as_float(bits); e.y = xw; }
                    else        { e.z = __int_as_float(bits); e.w = xw; }
                }
                s_colp[slot * 7 + xg] = e;
            }
        }
        __syncthreads();

        const int total = cnt * PAIRS;         // pairs in this chunk
        for (int q = tid; q < total; q += 1024) {
            const int slot = q / PAIRS;        // magic mul
            const int rem  = q - slot * PAIRS;
            const int y    = rem / 7;          // magic mul
            const int xg   = rem - y * 7;

            const f2u re = s_row[slot * CROP_H + y];
            const f4u ce = s_colp[slot * 7 + xg];
            const int ri  = __float_as_int(re.x);
            const float yw = re.y;
            const int offr = ri & 0x3FFF;
            const bool sely = (ri & 0x4000) != 0;
            const bool vy   = (ri & 0x8000) != 0;

            f2u res;
            #pragma unroll
            for (int k = 0; k < 2; ++k) {
                const int ci   = __float_as_int(k ? ce.z : ce.x);
                const float xw = k ? ce.w : ce.y;
                const float* pp = s_plane + (offr + (ci & 0xFF));
                const float a0 = pp[0];
                const float a1 = pp[1];
                const float b0 = pp[IMG_W];
                const float b1 = pp[IMG_W + 1];

                const float tA = sely ? b0 : a0;
                const float tB = sely ? b1 : a1;
                const float tl = (ci & 0x100) ? tB : tA;
                const float bl = (ci & 0x100) ? b1 : b0;

                const float top_v = __fadd_rn(tl, __fmul_rn(__fsub_rn(tB, tl), xw));
                const float bot_v = __fadd_rn(bl, __fmul_rn(__fsub_rn(b1, bl), xw));
                const float v = __fadd_rn(top_v, __fmul_rn(__fsub_rn(bot_v, top_v), yw));
                const bool vald = vy && (ci & 0x200);
                res[k] = vald ? v : 0.0f;
            }

            *(f2u*)(out + (size_t)(s_ob[slot] + cPOS + (unsigned)(2 * q - slot * POS + 0)
                                   - (unsigned)(2 * rem) + (unsigned)(y * CROP_W + 2 * xg))) = res;
        }
    }
}

// ---------------------------------------------------------------------------
// Fallback (R5 structure, known 104 us) if workspace is too small.
// ---------------------------------------------------------------------------
__global__ __launch_bounds__(256) void crop_chw_kernel(
    const float* __restrict__ image,
    const float* __restrict__ boxes,
    const int* __restrict__ box_ind,
    float* __restrict__ out)
{
    const int bid  = blockIdx.x;
    const int cg   = bid & 7;
    const int n    = bid >> 3;
    const int tid  = threadIdx.x;
    if (tid >= POS) return;

    const int b = box_ind[n];
    const int y = tid / CROP_W;
    const int x = tid - y * CROP_W;

    const float y1 = boxes[n * 4 + 0];
    const float x1 = boxes[n * 4 + 1];
    const float y2 = boxes[n * 4 + 2];
    const float x2 = boxes[n * 4 + 3];

    const float hs   = __fdiv_rn(__fmul_rn(__fsub_rn(y2, y1), (float)(IMG_H - 1)),
                                 (float)(CROP_H - 1));
    const float in_y = __fadd_rn(__fmul_rn(y1, (float)(IMG_H - 1)),
                                 __fmul_rn((float)y, hs));
    const int vy = (in_y >= 0.0f) && (in_y <= (float)(IMG_H - 1));
    const float top = floorf(in_y);
    const float yw  = __fsub_rn(in_y, top);
    const int ti = (int)fminf(fmaxf(top, 0.0f), (float)(IMG_H - 1));

    const float ws   = __fdiv_rn(__fmul_rn(__fsub_rn(x2, x1), (float)(IMG_W - 1)),
                                 (float)(CROP_W - 1));
    const float in_x = __fadd_rn(__fmul_rn(x1, (float)(IMG_W - 1)),
                                 __fmul_rn((float)x, ws));
    const int vx = (in_x >= 0.0f) && (in_x <= (float)(IMG_W - 1));
    const float left = floorf(in_x);
    const float xw   = __fsub_rn(in_x, left);
    const int li = (int)fminf(fmaxf(left, 0.0f), (float)(IMG_W - 1));

    const int r0 = min(ti, IMG_H - 2);
    const int c0 = min(li, IMG_W - 2);
    const bool sely = (ti == IMG_H - 1);
    const bool selx = (li == IMG_W - 1);
    const bool vald = (vy & vx) != 0;

    const float* __restrict__ pl =
        image + (size_t)b * (size_t)(IMG_C * PLANE)
              + (size_t)(cg * CG) * PLANE + (r0 * IMG_W + c0);
    float* __restrict__ po =
        out + (size_t)n * (size_t)OUT_PER_BOX + (size_t)(cg * CG) * POS + tid;

    #pragma unroll 8
    for (int cl = 0; cl < CG; ++cl) {
        const float2 ra = *(const float2*)(pl);
        const float2 rb = *(const float2*)(pl + IMG_W);
        const float tA = sely ? rb.x : ra.x;
        const float tB = sely ? rb.y : ra.y;
        const float tl = selx ? tB : tA;
        const float bl = selx ? rb.y : rb.x;
        const float top_v = __fadd_rn(tl, __fmul_rn(__fsub_rn(tB, tl), xw));
        const float bot_v = __fadd_rn(bl, __fmul_rn(__fsub_rn(rb.y, bl), xw));
        const float v = __fadd_rn(top_v, __fmul_rn(__fsub_rn(bot_v, top_v), yw));
        *po = vald ? v : 0.0f;
        pl += PLANE;
        po += POS;
    }
}

extern "C" void kernel_launch(void* const* d_in, const int* in_sizes, int n_in,
                              void* d_out, int out_size, void* d_ws, size_t ws_size,
                              hipStream_t stream) {
    const float* image  = (const float*)d_in[0];
    const float* boxes  = (const float*)d_in[1];
    const int*   boxind = (const int*)d_in[2];
    float* out = (float*)d_out;

    const size_t need = (NBOX + IMG_B + 1) * sizeof(int);
    if (ws_size >= need) {
        int* perm    = (int*)d_ws;
        int* offsets = perm + NBOX;

        sort_boxes_kernel<<<1, 1024, 0, stream>>>(boxind, perm, offsets);
        CropAndResize_16630113370849_kernel<<<dim3(IMG_C, IMG_B), 1024, 0, stream>>>(
            image, boxes, perm, offsets, out);
    } else {
        crop_chw_kernel<<<dim3(NBOX * NCG), 256, 0, stream>>>(
            image, boxes, boxind, out);
    }
}